// Round 18
// baseline (31.588 us; speedup 1.0000x reference)
//
#include <hip/hip_runtime.h>
#include <math.h>

// SoftHd via bf16 MFMA. R16 base (A once->LDS, B direct->VGPR, barrier-free
// K loop, DPP epilogue, 2 pairs/block, dead-quadrant skip) + MFMA-ONLY
// fragment skip: loads/epilogue stay unconditional (preserves the compiler's
// vmcnt batching, which R17's load guards broke); only MFMA issue is guarded
// by wave-uniform scalar tests. Skipped MFMAs leave acc=0, and the +INF
// operand masking makes those epilogue values +INF -> bit-identical results.
// out[b1,b2] = sum_{j<sz2} min_{i<sz1} dist[i,j] + sum_{i<sz1} min_{j<sz2} dist[i,j]
// dist via gemm identity on bf16-rounded inputs; sqrt monotone -> mins on
// squared distances, sqrt after reduction; masking folded into +INF operands.
// Quarter-blocked global bf16 layout (pre-kernel):
//   panel byte off(r,c16) = (c16>>2)*8192 + (r>>3)*512 + (c16&3)*128 + (r&7)*16

typedef __attribute__((ext_vector_type(8))) short short8;
typedef __attribute__((ext_vector_type(4))) float f32x4;
typedef unsigned int u32;
typedef unsigned short ushort_t;

static __device__ __forceinline__ ushort_t f32_to_bf16_rne(float f) {
    u32 b = __float_as_uint(f);
    b += 0x7FFFu + ((b >> 16) & 1u);
    return (ushort_t)(b >> 16);
}

// DPP quad_perm folds (VALU pipe): xor1 = 0xB1, xor2 = 0x4E.
#define DPPX1(x) __int_as_float(__builtin_amdgcn_update_dpp( \
    0, __float_as_int(x), 0xB1, 0xF, 0xF, true))
#define DPPX2(x) __int_as_float(__builtin_amdgcn_update_dpp( \
    0, __float_as_int(x), 0x4E, 0xF, 0xF, true))

// ---------------------------------------------------------------------------
// Pre-kernel: f32 -> bf16 into quarter-blocked layout + per-row squared norms
// (fp32 of the ROUNDED values).
// ---------------------------------------------------------------------------
__global__ __launch_bounds__(256) void softhd_pre(
    const float* __restrict__ v1, const float* __restrict__ v2,
    ushort_t* __restrict__ v1b, ushort_t* __restrict__ v2b,
    float* __restrict__ x2g, float* __restrict__ y2g)
{
    int flat = blockIdx.x * 256 + threadIdx.x;
    int c = flat & 15;
    int r = (flat >> 4) & 127;
    int b = (flat >> 11) & 63;
    int t = flat >> 17;

    const float* src = (t ? v2 : v1) + ((size_t)((b << 7) + r) << 7) + c * 8;
    char* dstp = (char*)((t ? v2b : v1b) + ((size_t)b << 14));

    float4 q0 = *(const float4*)(src);
    float4 q1 = *(const float4*)(src + 4);

    ushort_t h[8];
    h[0] = f32_to_bf16_rne(q0.x); h[1] = f32_to_bf16_rne(q0.y);
    h[2] = f32_to_bf16_rne(q0.z); h[3] = f32_to_bf16_rne(q0.w);
    h[4] = f32_to_bf16_rne(q1.x); h[5] = f32_to_bf16_rne(q1.y);
    h[6] = f32_to_bf16_rne(q1.z); h[7] = f32_to_bf16_rne(q1.w);

    float p = 0.f;
#pragma unroll
    for (int k = 0; k < 8; ++k) {
        float fv = __uint_as_float((u32)h[k] << 16);
        p += fv * fv;
    }

    uint4 w;
    w.x = (u32)h[0] | ((u32)h[1] << 16);
    w.y = (u32)h[2] | ((u32)h[3] << 16);
    w.z = (u32)h[4] | ((u32)h[5] << 16);
    w.w = (u32)h[6] | ((u32)h[7] << 16);

    int off = ((c >> 2) << 13) + ((r >> 3) << 9) + ((c & 3) << 7) + ((r & 7) << 4);
    *(uint4*)(dstp + off) = w;

    p += __shfl_xor(p, 1);
    p += __shfl_xor(p, 2);
    p += __shfl_xor(p, 4);
    p += __shfl_xor(p, 8);
    if (c == 0) (t ? y2g : x2g)[(b << 7) + r] = p;
}

// ---------------------------------------------------------------------------
// Main kernel: 2048 blocks = 64 b1 x 32 b2-pairs. 4 waves, 2x2 quadrant split
// per pair (64x64 out per wave). A panel (32 KB) in LDS; B direct to VGPR.
// ---------------------------------------------------------------------------
__global__ __launch_bounds__(256, 3) void softhd_mfma(
    const ushort_t* __restrict__ v1b, const ushort_t* __restrict__ v2b,
    const float* __restrict__ x2g, const float* __restrict__ y2g,
    const int* __restrict__ sz1, const int* __restrict__ sz2,
    float* __restrict__ out)
{
    __shared__ __align__(16) ushort_t sA[4 * 4096];    // full A panel, 32 KB
    __shared__ float sx2[128], sy2[2][128];
    __shared__ u32 sbm1[2][128], sbm2[2][128];
    __shared__ float swsum[4];

    const int tid = threadIdx.x;
    const int lane = tid & 63;
    const int wid = tid >> 6;
    // XCD-bijective swizzle (2048 % 8 == 0).
    const int bid = ((blockIdx.x & 7) << 8) | (blockIdx.x >> 3);
    const int b1 = bid >> 5;
    const int b2base = (bid & 31) << 1;

    const char* gA = (const char*)(v1b + ((size_t)b1 << 14));
    const char* gB0 = (const char*)(v2b + ((size_t)(b2base + 0) << 14));
    const char* gB1 = (const char*)(v2b + ((size_t)(b2base + 1) << 14));

    const int n1 = min(max(sz1[b1], 0), 128);
    int n2v[2];
    n2v[0] = min(max(sz2[b2base + 0], 0), 128);
    n2v[1] = min(max(sz2[b2base + 1], 0), 128);

    // A panel: 32 KB linear copy, 8 x 16B per thread. Odd e chunks are rows
    // 64-127 — only needed if n1 > 64.
    {
        const bool hiA = n1 > 64;
#pragma unroll
        for (int e = 0; e < 8; ++e) {
            if ((e & 1) == 0 || hiA) {
                int m16 = ((e << 8) + tid) << 4;
                __builtin_amdgcn_global_load_lds(
                    (const __attribute__((address_space(1))) u32*)(gA + m16),
                    (__attribute__((address_space(3))) u32*)((char*)&sA[0] + m16),
                    16, 0, 0);
            }
        }
    }

    if (tid < 128) {
        sx2[tid] = x2g[(b1 << 7) + tid];
    } else {
        sy2[0][tid - 128] = y2g[((b2base + 0) << 7) + (tid - 128)];
        sy2[1][tid - 128] = y2g[((b2base + 1) << 7) + (tid - 128)];
    }
    ((u32*)sbm1)[tid] = 0x7F800000u;        // +inf bits (2x128 slots)
    ((u32*)sbm2)[tid] = 0x7F800000u;
    __syncthreads();                        // A resident + init visible

    const int qr = wid >> 1, qc = wid & 1;
    const int ibase = qr << 6, jbase = qc << 6;
    const int rf = lane & 15, kg = lane >> 4;
    const bool h0 = lane & 1, h1 = lane & 2, h2 = lane & 4, h3 = lane & 8;
    const bool h4 = lane & 16, h5 = lane & 32;

    // Wave-uniform live extents (readfirstlane -> provably scalar branches).
    const int ibu = __builtin_amdgcn_readfirstlane(ibase);
    const int jbu = __builtin_amdgcn_readfirstlane(jbase);
    const int liveI  = n1 - ibu;
    const int liveJ0 = n2v[0] - jbu;
    const int liveJ1 = n2v[1] - jbu;
    const bool act0 = (liveI > 0) && (liveJ0 > 0);
    const bool act1 = (liveI > 0) && (liveJ1 > 0);

    // A frag elem offsets within an 8 KB quarter: (row>>3)*256 + kg*64 + (row&7)*8
    // B frag BYTE offsets within a quarter block:  (row>>3)*512 + kg*128 + (row&7)*16
    int aoff[4], boffB[4];
#pragma unroll
    for (int f = 0; f < 4; ++f) {
        int ra = ibase + (f << 4) + rf;
        int rb = jbase + (f << 4) + rf;
        aoff[f]  = ((ra >> 3) << 8) + (kg << 6) + ((ra & 7) << 3);
        boffB[f] = ((rb >> 3) << 9) + (kg << 7) + ((rb & 7) << 4);
    }

    f32x4 acc[4][4];
#pragma unroll
    for (int fi = 0; fi < 4; ++fi)
#pragma unroll
        for (int fj = 0; fj < 4; ++fj)
            acc[fi][fj] = (f32x4){0.f, 0.f, 0.f, 0.f};

// Loads stay UNCONDITIONAL (R15/R16-proven scheduling).
#define LOADB(B, gB, q)                                                      \
    {                                                                        \
        _Pragma("unroll")                                                    \
        for (int f = 0; f < 4; ++f)                                          \
            B[f] = *(const short8*)((gB) + ((q) << 13) + boffB[f]);          \
    }
// Only MFMA issue is guarded (wave-uniform scalar -> s_cbranch). Skipped
// MFMAs leave acc=0; epilogue's +INF operand masking covers those (i,j).
#define COMP(B, q, LI, LJ)                                                   \
    {                                                                        \
        short8 a[4];                                                         \
        _Pragma("unroll")                                                    \
        for (int f = 0; f < 4; ++f)                                          \
            a[f] = *(const short8*)(&sA[(q) << 12] + aoff[f]);               \
        __builtin_amdgcn_s_setprio(1);                                       \
        _Pragma("unroll")                                                    \
        for (int fi = 0; fi < 4; ++fi)                                       \
            if ((fi << 4) < (LI)) {                                          \
                _Pragma("unroll")                                            \
                for (int fj = 0; fj < 4; ++fj)                               \
                    if ((fj << 4) < (LJ))                                    \
                        acc[fi][fj] = __builtin_amdgcn_mfma_f32_16x16x32_bf16(\
                            a[fi], B[fj], acc[fi][fj], 0, 0, 0);             \
            }                                                                \
        __builtin_amdgcn_s_setprio(0);                                       \
    }

    const float INF = __builtin_inff();

    // DPP epilogue (R13-R16-verified), UNCONDITIONAL, pair-indexed.
#define EPILOGUE(p)                                                          \
    {                                                                        \
        const int nn2 = n2v[p];                                              \
        float yje[4];                                                        \
        _Pragma("unroll")                                                    \
        for (int fj = 0; fj < 4; ++fj) {                                     \
            int j = jbase + (fj << 4) + rf;                                  \
            yje[fj] = (j < nn2) ? sy2[p][j] : INF;                           \
        }                                                                    \
        float minj[4] = {INF, INF, INF, INF};                                \
        float mini4[4];                                                      \
        _Pragma("unroll")                                                    \
        for (int fi = 0; fi < 4; ++fi) {                                     \
            const int i0 = ibase + (fi << 4) + (kg << 2);                    \
            float4 xs = *(const float4*)&sx2[i0];                            \
            float xie[4];                                                    \
            xie[0] = (i0 + 0 < n1) ? xs.x : INF;                             \
            xie[1] = (i0 + 1 < n1) ? xs.y : INF;                             \
            xie[2] = (i0 + 2 < n1) ? xs.z : INF;                             \
            xie[3] = (i0 + 3 < n1) ? xs.w : INF;                             \
            float u[4][4];                                                   \
            _Pragma("unroll")                                                \
            for (int fj = 0; fj < 4; ++fj) {                                 \
                _Pragma("unroll")                                            \
                for (int q = 0; q < 4; ++q)                                  \
                    u[fj][q] = fmaf(acc[fi][fj][q], -2.f, xie[q] + yje[fj]); \
                minj[fj] = fminf(fminf(minj[fj], u[fj][0]), u[fj][1]);       \
                minj[fj] = fminf(fminf(minj[fj], u[fj][2]), u[fj][3]);       \
            }                                                                \
            float mq0 = fminf(fminf(u[0][0], u[1][0]), fminf(u[2][0], u[3][0])); \
            float mq1 = fminf(fminf(u[0][1], u[1][1]), fminf(u[2][1], u[3][1])); \
            float mq2 = fminf(fminf(u[0][2], u[1][2]), fminf(u[2][2], u[3][2])); \
            float mq3 = fminf(fminf(u[0][3], u[1][3]), fminf(u[2][3], u[3][3])); \
            float pa = fminf(mq0, DPPX1(mq0));                               \
            float pb = fminf(mq1, DPPX1(mq1));                               \
            float r01 = h0 ? pb : pa;                                        \
            pa = fminf(mq2, DPPX1(mq2));                                     \
            pb = fminf(mq3, DPPX1(mq3));                                     \
            float r23 = h0 ? pb : pa;                                        \
            pa = fminf(r01, DPPX2(r01));                                     \
            pb = fminf(r23, DPPX2(r23));                                     \
            mini4[fi] = h1 ? pb : pa;                                        \
        }                                                                    \
        {                                                                    \
            float pa = fminf(mini4[0], __shfl_xor(mini4[0], 4));             \
            float pb = fminf(mini4[1], __shfl_xor(mini4[1], 4));             \
            float A = h2 ? pb : pa;                                          \
            pa = fminf(mini4[2], __shfl_xor(mini4[2], 4));                   \
            pb = fminf(mini4[3], __shfl_xor(mini4[3], 4));                   \
            float B = h2 ? pb : pa;                                          \
            pa = fminf(A, __shfl_xor(A, 8));                                 \
            pb = fminf(B, __shfl_xor(B, 8));                                 \
            float Mi = h3 ? pb : pa;                                         \
            float dmin = __builtin_amdgcn_sqrtf(fmaxf(Mi, 0.f));             \
            int ii = ibase + ((rf >> 2) << 4) + (kg << 2) + (rf & 3);        \
            atomicMin(&sbm2[p][ii], __float_as_uint(dmin));                  \
        }                                                                    \
        {                                                                    \
            float pa = fminf(minj[0], __shfl_xor(minj[0], 32));              \
            float pb = fminf(minj[1], __shfl_xor(minj[1], 32));              \
            float A = h5 ? pb : pa;                                          \
            pa = fminf(minj[2], __shfl_xor(minj[2], 32));                    \
            pb = fminf(minj[3], __shfl_xor(minj[3], 32));                    \
            float B = h5 ? pb : pa;                                          \
            pa = fminf(A, __shfl_xor(A, 16));                                \
            pb = fminf(B, __shfl_xor(B, 16));                                \
            float Mj = h4 ? pb : pa;                                         \
            float dminj = __builtin_amdgcn_sqrtf(fmaxf(Mj, 0.f));            \
            int fjf = ((lane >> 5) & 1) | (((lane >> 4) & 1) << 1);          \
            atomicMin(&sbm1[p][jbase + (fjf << 4) + rf], __float_as_uint(dminj)); \
        }                                                                    \
    }

    short8 bfA[4], bfB[4];

    // ---- pair 0 (only if this wave's quadrant is live) ----
    if (act0) {
        LOADB(bfA, gB0, 0); LOADB(bfB, gB0, 1);
        COMP(bfA, 0, liveI, liveJ0); LOADB(bfA, gB0, 2);
        COMP(bfB, 1, liveI, liveJ0); LOADB(bfB, gB0, 3);
        COMP(bfA, 2, liveI, liveJ0);
        COMP(bfB, 3, liveI, liveJ0);
        if (act1) { LOADB(bfA, gB1, 0); LOADB(bfB, gB1, 1); }  // prefetch
        EPILOGUE(0);
    }

    // ---- pair 1 ----
    if (act1) {
#pragma unroll
        for (int fi = 0; fi < 4; ++fi)
#pragma unroll
            for (int fj = 0; fj < 4; ++fj)
                acc[fi][fj] = (f32x4){0.f, 0.f, 0.f, 0.f};
        if (!act0) { LOADB(bfA, gB1, 0); LOADB(bfB, gB1, 1); }
        COMP(bfA, 0, liveI, liveJ1); LOADB(bfA, gB1, 2);
        COMP(bfB, 1, liveI, liveJ1); LOADB(bfB, gB1, 3);
        COMP(bfA, 2, liveI, liveJ1);
        COMP(bfB, 3, liveI, liveJ1);
        EPILOGUE(1);
    }

#undef LOADB
#undef COMP
#undef EPILOGUE

    __syncthreads();                        // atomics visible

    // Final reduce: threads 0-127 -> pair 0, 128-255 -> pair 1.
    {
        const int p = tid >> 7;
        const int e = tid & 127;
        const int nn2 = n2v[p];
        float v = 0.f;
        if (n1 > 0 && e < nn2) v += __uint_as_float(sbm1[p][e]);
        if (nn2 > 0 && e < n1) v += __uint_as_float(sbm2[p][e]);
#pragma unroll
        for (int off = 32; off >= 1; off >>= 1) v += __shfl_down(v, off);
        if (lane == 0) swsum[wid] = v;
    }
    __syncthreads();
    if (tid == 0)   out[(b1 << 6) + b2base + 0] = swsum[0] + swsum[1];
    if (tid == 128) out[(b1 << 6) + b2base + 1] = swsum[2] + swsum[3];
}

extern "C" void kernel_launch(void* const* d_in, const int* in_sizes, int n_in,
                              void* d_out, int out_size, void* d_ws, size_t ws_size,
                              hipStream_t stream) {
    const float* v1  = (const float*)d_in[0];
    const int*   sz1 = (const int*)d_in[1];
    const float* v2  = (const float*)d_in[2];
    const int*   sz2 = (const int*)d_in[3];
    float* out = (float*)d_out;
    (void)in_sizes; (void)n_in; (void)out_size; (void)ws_size;

    char* ws = (char*)d_ws;
    ushort_t* v1b = (ushort_t*)ws;                       // 2 MB
    ushort_t* v2b = (ushort_t*)(ws + (2u << 20));        // 2 MB
    float*    x2g = (float*)(ws + (4u << 20));           // 32 KB
    float*    y2g = x2g + 64 * 128;                      // 32 KB

    softhd_pre<<<dim3(1024), dim3(256), 0, stream>>>(v1, v2, v1b, v2b, x2g, y2g);
    softhd_mfma<<<dim3(2048), dim3(256), 0, stream>>>(v1b, v2b, x2g, y2g,
                                                      sz1, sz2, out);
}

// Round 19
// 29.862 us; speedup vs baseline: 1.0578x; 1.0578x over previous
//
#include <hip/hip_runtime.h>
#include <math.h>

// SoftHd via bf16 MFMA — FINAL (R16 best, exact reversion).
// Structure: pre-kernel converts f32->bf16 into a quarter-blocked layout +
// per-row squared norms; main kernel = 2048 blocks (64 b1 x 32 b2-pairs),
// 4 waves in 2x2 quadrant split per pair, A panel staged once into LDS
// (global_load_lds w=16, upper half skipped when n1<=64), B fragments loaded
// directly global->VGPR (barrier-free K loop, compiler-managed vmcnt),
// dead-quadrant wave skip, DPP/VALU-pipe merge-reduce epilogue, sqrt after
// reduction (monotonicity), masking folded into +INF operands, single
// end-of-kernel reduce.
// out[b1,b2] = sum_{j<sz2} min_{i<sz1} dist[i,j] + sum_{i<sz1} min_{j<sz2} dist[i,j]
// Quarter-blocked global bf16 layout:
//   panel byte off(r,c16) = (c16>>2)*8192 + (r>>3)*512 + (c16&3)*128 + (r&7)*16
//
// Lessons encoded here (R0-R18): work cuts pay proportionally (6/6 wins);
// schedule-only changes are neutral (additive multi-pipe floor); ANY scalar
// branch inside the K-loop body regresses (R17/R18) — only whole-pipeline
// skips (act0/act1) are profitable.

typedef __attribute__((ext_vector_type(8))) short short8;
typedef __attribute__((ext_vector_type(4))) float f32x4;
typedef unsigned int u32;
typedef unsigned short ushort_t;

static __device__ __forceinline__ ushort_t f32_to_bf16_rne(float f) {
    u32 b = __float_as_uint(f);
    b += 0x7FFFu + ((b >> 16) & 1u);
    return (ushort_t)(b >> 16);
}

// DPP quad_perm folds (VALU pipe): xor1 = 0xB1, xor2 = 0x4E.
#define DPPX1(x) __int_as_float(__builtin_amdgcn_update_dpp( \
    0, __float_as_int(x), 0xB1, 0xF, 0xF, true))
#define DPPX2(x) __int_as_float(__builtin_amdgcn_update_dpp( \
    0, __float_as_int(x), 0x4E, 0xF, 0xF, true))

// ---------------------------------------------------------------------------
// Pre-kernel: f32 -> bf16 into quarter-blocked layout + per-row squared norms
// (fp32 of the ROUNDED values).
// ---------------------------------------------------------------------------
__global__ __launch_bounds__(256) void softhd_pre(
    const float* __restrict__ v1, const float* __restrict__ v2,
    ushort_t* __restrict__ v1b, ushort_t* __restrict__ v2b,
    float* __restrict__ x2g, float* __restrict__ y2g)
{
    int flat = blockIdx.x * 256 + threadIdx.x;
    int c = flat & 15;
    int r = (flat >> 4) & 127;
    int b = (flat >> 11) & 63;
    int t = flat >> 17;

    const float* src = (t ? v2 : v1) + ((size_t)((b << 7) + r) << 7) + c * 8;
    char* dstp = (char*)((t ? v2b : v1b) + ((size_t)b << 14));

    float4 q0 = *(const float4*)(src);
    float4 q1 = *(const float4*)(src + 4);

    ushort_t h[8];
    h[0] = f32_to_bf16_rne(q0.x); h[1] = f32_to_bf16_rne(q0.y);
    h[2] = f32_to_bf16_rne(q0.z); h[3] = f32_to_bf16_rne(q0.w);
    h[4] = f32_to_bf16_rne(q1.x); h[5] = f32_to_bf16_rne(q1.y);
    h[6] = f32_to_bf16_rne(q1.z); h[7] = f32_to_bf16_rne(q1.w);

    float p = 0.f;
#pragma unroll
    for (int k = 0; k < 8; ++k) {
        float fv = __uint_as_float((u32)h[k] << 16);
        p += fv * fv;
    }

    uint4 w;
    w.x = (u32)h[0] | ((u32)h[1] << 16);
    w.y = (u32)h[2] | ((u32)h[3] << 16);
    w.z = (u32)h[4] | ((u32)h[5] << 16);
    w.w = (u32)h[6] | ((u32)h[7] << 16);

    int off = ((c >> 2) << 13) + ((r >> 3) << 9) + ((c & 3) << 7) + ((r & 7) << 4);
    *(uint4*)(dstp + off) = w;

    p += __shfl_xor(p, 1);
    p += __shfl_xor(p, 2);
    p += __shfl_xor(p, 4);
    p += __shfl_xor(p, 8);
    if (c == 0) (t ? y2g : x2g)[(b << 7) + r] = p;
}

// ---------------------------------------------------------------------------
// Main kernel: 2048 blocks = 64 b1 x 32 b2-pairs. 4 waves, 2x2 quadrant split
// per pair (64x64 out per wave). A panel (32 KB) in LDS; B direct to VGPR.
// ---------------------------------------------------------------------------
__global__ __launch_bounds__(256, 3) void softhd_mfma(
    const ushort_t* __restrict__ v1b, const ushort_t* __restrict__ v2b,
    const float* __restrict__ x2g, const float* __restrict__ y2g,
    const int* __restrict__ sz1, const int* __restrict__ sz2,
    float* __restrict__ out)
{
    __shared__ __align__(16) ushort_t sA[4 * 4096];    // full A panel, 32 KB
    __shared__ float sx2[128], sy2[2][128];
    __shared__ u32 sbm1[2][128], sbm2[2][128];
    __shared__ float swsum[4];

    const int tid = threadIdx.x;
    const int lane = tid & 63;
    const int wid = tid >> 6;
    // XCD-bijective swizzle (2048 % 8 == 0).
    const int bid = ((blockIdx.x & 7) << 8) | (blockIdx.x >> 3);
    const int b1 = bid >> 5;
    const int b2base = (bid & 31) << 1;

    const char* gA = (const char*)(v1b + ((size_t)b1 << 14));
    const char* gB0 = (const char*)(v2b + ((size_t)(b2base + 0) << 14));
    const char* gB1 = (const char*)(v2b + ((size_t)(b2base + 1) << 14));

    const int n1 = min(max(sz1[b1], 0), 128);
    int n2v[2];
    n2v[0] = min(max(sz2[b2base + 0], 0), 128);
    n2v[1] = min(max(sz2[b2base + 1], 0), 128);

    // A panel: 32 KB linear copy, 8 x 16B per thread. Odd e chunks are rows
    // 64-127 — only needed if n1 > 64.
    {
        const bool hiA = n1 > 64;
#pragma unroll
        for (int e = 0; e < 8; ++e) {
            if ((e & 1) == 0 || hiA) {
                int m16 = ((e << 8) + tid) << 4;
                __builtin_amdgcn_global_load_lds(
                    (const __attribute__((address_space(1))) u32*)(gA + m16),
                    (__attribute__((address_space(3))) u32*)((char*)&sA[0] + m16),
                    16, 0, 0);
            }
        }
    }

    if (tid < 128) {
        sx2[tid] = x2g[(b1 << 7) + tid];
    } else {
        sy2[0][tid - 128] = y2g[((b2base + 0) << 7) + (tid - 128)];
        sy2[1][tid - 128] = y2g[((b2base + 1) << 7) + (tid - 128)];
    }
    ((u32*)sbm1)[tid] = 0x7F800000u;        // +inf bits (2x128 slots)
    ((u32*)sbm2)[tid] = 0x7F800000u;
    __syncthreads();                        // A resident + init visible

    const int qr = wid >> 1, qc = wid & 1;
    const int ibase = qr << 6, jbase = qc << 6;
    const int rf = lane & 15, kg = lane >> 4;
    const bool h0 = lane & 1, h1 = lane & 2, h2 = lane & 4, h3 = lane & 8;
    const bool h4 = lane & 16, h5 = lane & 32;

    // Dead-quadrant skip (wave-uniform): a wave with all i >= n1 or all
    // j >= n2 contributes only +INF atomicMins / never-read slots.
    const bool act0 = (ibase < n1) && (jbase < n2v[0]);
    const bool act1 = (ibase < n1) && (jbase < n2v[1]);

    // A frag elem offsets within an 8 KB quarter: (row>>3)*256 + kg*64 + (row&7)*8
    // B frag BYTE offsets within a quarter block:  (row>>3)*512 + kg*128 + (row&7)*16
    int aoff[4], boffB[4];
#pragma unroll
    for (int f = 0; f < 4; ++f) {
        int ra = ibase + (f << 4) + rf;
        int rb = jbase + (f << 4) + rf;
        aoff[f]  = ((ra >> 3) << 8) + (kg << 6) + ((ra & 7) << 3);
        boffB[f] = ((rb >> 3) << 9) + (kg << 7) + ((rb & 7) << 4);
    }

    f32x4 acc[4][4];
#pragma unroll
    for (int fi = 0; fi < 4; ++fi)
#pragma unroll
        for (int fj = 0; fj < 4; ++fj)
            acc[fi][fj] = (f32x4){0.f, 0.f, 0.f, 0.f};

#define LOADB(B, gB, q)                                                      \
    {                                                                        \
        _Pragma("unroll")                                                    \
        for (int f = 0; f < 4; ++f)                                          \
            B[f] = *(const short8*)((gB) + ((q) << 13) + boffB[f]);          \
    }
#define COMP(B, q)                                                           \
    {                                                                        \
        short8 a[4];                                                         \
        _Pragma("unroll")                                                    \
        for (int f = 0; f < 4; ++f)                                          \
            a[f] = *(const short8*)(&sA[(q) << 12] + aoff[f]);               \
        __builtin_amdgcn_s_setprio(1);                                       \
        _Pragma("unroll")                                                    \
        for (int fi = 0; fi < 4; ++fi)                                       \
            _Pragma("unroll")                                                \
            for (int fj = 0; fj < 4; ++fj)                                   \
                acc[fi][fj] = __builtin_amdgcn_mfma_f32_16x16x32_bf16(       \
                    a[fi], B[fj], acc[fi][fj], 0, 0, 0);                     \
        __builtin_amdgcn_s_setprio(0);                                       \
    }

    const float INF = __builtin_inff();

    // DPP epilogue (R13-R16-verified), pair-indexed sbm/sy2/n2.
#define EPILOGUE(p)                                                          \
    {                                                                        \
        const int nn2 = n2v[p];                                              \
        float yje[4];                                                        \
        _Pragma("unroll")                                                    \
        for (int fj = 0; fj < 4; ++fj) {                                     \
            int j = jbase + (fj << 4) + rf;                                  \
            yje[fj] = (j < nn2) ? sy2[p][j] : INF;                           \
        }                                                                    \
        float minj[4] = {INF, INF, INF, INF};                                \
        float mini4[4];                                                      \
        _Pragma("unroll")                                                    \
        for (int fi = 0; fi < 4; ++fi) {                                     \
            const int i0 = ibase + (fi << 4) + (kg << 2);                    \
            float4 xs = *(const float4*)&sx2[i0];                            \
            float xie[4];                                                    \
            xie[0] = (i0 + 0 < n1) ? xs.x : INF;                             \
            xie[1] = (i0 + 1 < n1) ? xs.y : INF;                             \
            xie[2] = (i0 + 2 < n1) ? xs.z : INF;                             \
            xie[3] = (i0 + 3 < n1) ? xs.w : INF;                             \
            float u[4][4];                                                   \
            _Pragma("unroll")                                                \
            for (int fj = 0; fj < 4; ++fj) {                                 \
                _Pragma("unroll")                                            \
                for (int q = 0; q < 4; ++q)                                  \
                    u[fj][q] = fmaf(acc[fi][fj][q], -2.f, xie[q] + yje[fj]); \
                minj[fj] = fminf(fminf(minj[fj], u[fj][0]), u[fj][1]);       \
                minj[fj] = fminf(fminf(minj[fj], u[fj][2]), u[fj][3]);       \
            }                                                                \
            float mq0 = fminf(fminf(u[0][0], u[1][0]), fminf(u[2][0], u[3][0])); \
            float mq1 = fminf(fminf(u[0][1], u[1][1]), fminf(u[2][1], u[3][1])); \
            float mq2 = fminf(fminf(u[0][2], u[1][2]), fminf(u[2][2], u[3][2])); \
            float mq3 = fminf(fminf(u[0][3], u[1][3]), fminf(u[2][3], u[3][3])); \
            float pa = fminf(mq0, DPPX1(mq0));                               \
            float pb = fminf(mq1, DPPX1(mq1));                               \
            float r01 = h0 ? pb : pa;                                        \
            pa = fminf(mq2, DPPX1(mq2));                                     \
            pb = fminf(mq3, DPPX1(mq3));                                     \
            float r23 = h0 ? pb : pa;                                        \
            pa = fminf(r01, DPPX2(r01));                                     \
            pb = fminf(r23, DPPX2(r23));                                     \
            mini4[fi] = h1 ? pb : pa;                                        \
        }                                                                    \
        {                                                                    \
            float pa = fminf(mini4[0], __shfl_xor(mini4[0], 4));             \
            float pb = fminf(mini4[1], __shfl_xor(mini4[1], 4));             \
            float A = h2 ? pb : pa;                                          \
            pa = fminf(mini4[2], __shfl_xor(mini4[2], 4));                   \
            pb = fminf(mini4[3], __shfl_xor(mini4[3], 4));                   \
            float B = h2 ? pb : pa;                                          \
            pa = fminf(A, __shfl_xor(A, 8));                                 \
            pb = fminf(B, __shfl_xor(B, 8));                                 \
            float Mi = h3 ? pb : pa;                                         \
            float dmin = __builtin_amdgcn_sqrtf(fmaxf(Mi, 0.f));             \
            int ii = ibase + ((rf >> 2) << 4) + (kg << 2) + (rf & 3);        \
            atomicMin(&sbm2[p][ii], __float_as_uint(dmin));                  \
        }                                                                    \
        {                                                                    \
            float pa = fminf(minj[0], __shfl_xor(minj[0], 32));              \
            float pb = fminf(minj[1], __shfl_xor(minj[1], 32));              \
            float A = h5 ? pb : pa;                                          \
            pa = fminf(minj[2], __shfl_xor(minj[2], 32));                    \
            pb = fminf(minj[3], __shfl_xor(minj[3], 32));                    \
            float B = h5 ? pb : pa;                                          \
            pa = fminf(A, __shfl_xor(A, 16));                                \
            pb = fminf(B, __shfl_xor(B, 16));                                \
            float Mj = h4 ? pb : pa;                                         \
            float dminj = __builtin_amdgcn_sqrtf(fmaxf(Mj, 0.f));            \
            int fjf = ((lane >> 5) & 1) | (((lane >> 4) & 1) << 1);          \
            atomicMin(&sbm1[p][jbase + (fjf << 4) + rf], __float_as_uint(dminj)); \
        }                                                                    \
    }

    short8 bfA[4], bfB[4];

    // ---- pair 0 (only if this wave's quadrant is live) ----
    if (act0) {
        LOADB(bfA, gB0, 0); LOADB(bfB, gB0, 1);
        COMP(bfA, 0); LOADB(bfA, gB0, 2);
        COMP(bfB, 1); LOADB(bfB, gB0, 3);
        COMP(bfA, 2);
        COMP(bfB, 3);
        if (act1) { LOADB(bfA, gB1, 0); LOADB(bfB, gB1, 1); }  // prefetch
        EPILOGUE(0);
    }

    // ---- pair 1 ----
    if (act1) {
#pragma unroll
        for (int fi = 0; fi < 4; ++fi)
#pragma unroll
            for (int fj = 0; fj < 4; ++fj)
                acc[fi][fj] = (f32x4){0.f, 0.f, 0.f, 0.f};
        if (!act0) { LOADB(bfA, gB1, 0); LOADB(bfB, gB1, 1); }
        COMP(bfA, 0); LOADB(bfA, gB1, 2);
        COMP(bfB, 1); LOADB(bfB, gB1, 3);
        COMP(bfA, 2);
        COMP(bfB, 3);
        EPILOGUE(1);
    }

#undef LOADB
#undef COMP
#undef EPILOGUE

    __syncthreads();                        // atomics visible

    // Final reduce: threads 0-127 -> pair 0, 128-255 -> pair 1.
    {
        const int p = tid >> 7;
        const int e = tid & 127;
        const int nn2 = n2v[p];
        float v = 0.f;
        if (n1 > 0 && e < nn2) v += __uint_as_float(sbm1[p][e]);
        if (nn2 > 0 && e < n1) v += __uint_as_float(sbm2[p][e]);
#pragma unroll
        for (int off = 32; off >= 1; off >>= 1) v += __shfl_down(v, off);
        if (lane == 0) swsum[wid] = v;
    }
    __syncthreads();
    if (tid == 0)   out[(b1 << 6) + b2base + 0] = swsum[0] + swsum[1];
    if (tid == 128) out[(b1 << 6) + b2base + 1] = swsum[2] + swsum[3];
}

extern "C" void kernel_launch(void* const* d_in, const int* in_sizes, int n_in,
                              void* d_out, int out_size, void* d_ws, size_t ws_size,
                              hipStream_t stream) {
    const float* v1  = (const float*)d_in[0];
    const int*   sz1 = (const int*)d_in[1];
    const float* v2  = (const float*)d_in[2];
    const int*   sz2 = (const int*)d_in[3];
    float* out = (float*)d_out;
    (void)in_sizes; (void)n_in; (void)out_size; (void)ws_size;

    char* ws = (char*)d_ws;
    ushort_t* v1b = (ushort_t*)ws;                       // 2 MB
    ushort_t* v2b = (ushort_t*)(ws + (2u << 20));        // 2 MB
    float*    x2g = (float*)(ws + (4u << 20));           // 32 KB
    float*    y2g = x2g + 64 * 128;                      // 32 KB

    softhd_pre<<<dim3(1024), dim3(256), 0, stream>>>(v1, v2, v1b, v2b, x2g, y2g);
    softhd_mfma<<<dim3(2048), dim3(256), 0, stream>>>(v1b, v2b, x2g, y2g,
                                                      sz1, sz2, out);
}